// Round 13
// baseline (59.668 us; speedup 1.0000x reference)
//
#include <hip/hip_runtime.h>

#define NB 32768
#define NN 12
#define DD 64
#define OBSD 28
#define EPB 16            // batch elements per block (one MFMA N-tile)
#define NSLOT 136         // weight-fragment slots in d_ws

typedef __bf16 bf16x8 __attribute__((ext_vector_type(8)));
typedef __bf16 bf16x4 __attribute__((ext_vector_type(4)));
typedef __bf16 bf16x2 __attribute__((ext_vector_type(2)));
typedef float  f32x4  __attribute__((ext_vector_type(4)));
typedef float  f32x2  __attribute__((ext_vector_type(2)));

#define MFMA(a, b, c) __builtin_amdgcn_mfma_f32_16x16x32_bf16((a), (b), (c), 0, 0, 0)

__device__ __forceinline__ float tanh_fast(float x) {
    // tanh(x) = 1 - 2/(e^{2x}+1);  e^{2x} = 2^(x*2/ln2).  3 full-rate + 2 trans ops.
    float e = __builtin_amdgcn_exp2f(x * 2.885390081777927f);
    float r = __builtin_amdgcn_rcpf(e + 1.f);
    return __builtin_fmaf(-2.f, r, 1.f);
}

// pairwise tanh: packed full-rate ops (pk_mul/pk_add/pk_fma) around scalar trans
__device__ __forceinline__ f32x2 tanh2_fast(f32x2 x) {
    const f32x2 k   = {2.885390081777927f, 2.885390081777927f};
    const f32x2 one = {1.f, 1.f};
    const f32x2 m2  = {-2.f, -2.f};
    f32x2 xe = x * k;
    f32x2 e;
    e[0] = __builtin_amdgcn_exp2f(xe[0]);
    e[1] = __builtin_amdgcn_exp2f(xe[1]);
    f32x2 ep = e + one;
    f32x2 r;
    r[0] = __builtin_amdgcn_rcpf(ep[0]);
    r[1] = __builtin_amdgcn_rcpf(ep[1]);
    return __builtin_elementwise_fma(m2, r, one);
}

// adjacency sparsity (12 nodes, 11 edges + self loops = 34 nonzeros), grouped by output node
static constexpr int AC_OFF[13] = {0,5,8,11,13,16,19,21,24,27,29,32,34};
static constexpr int AC_M[34] = {0,1,4,7,10, 0,1,2, 1,2,3, 2,3, 0,4,5, 4,5,6, 5,6, 0,7,8, 7,8,9, 8,9, 0,10,11, 10,11};
static constexpr int AC_N[34] = {0,0,0,0,0, 1,1,1, 2,2,2, 3,3, 4,4,4, 5,5,5, 6,6, 7,7,7, 8,8,8, 9,9, 10,10,10, 11,11};

// ---------------------------------------------------------------------------
// prep: pack W^T into MFMA A-fragment layout, bf16, into d_ws.
// slot map: 0..31 gcn {gp1,gp2,gv1,gv2}: mat*8 + w*2 + ks
//           32..39 pol1: 32 + w*2 + ks
//           40..135 val1: 40 + w*24 + ks   (K=768 -> 24 ksteps)
// per (slot, lane): 8 bf16 = A[w*16 + (l&15)][ks*32 + (l>>4)*8 + i] = W[k][dout]
// ---------------------------------------------------------------------------
__global__ __launch_bounds__(256) void prep_weights(
    const float* __restrict__ gp1, const float* __restrict__ gp2,
    const float* __restrict__ gv1, const float* __restrict__ gv2,
    const float* __restrict__ pol1, const float* __restrict__ val1,
    __bf16* __restrict__ wsb)
{
    int gid = blockIdx.x * blockDim.x + threadIdx.x;
    if (gid >= NSLOT * 64) return;
    int slot = gid >> 6, l = gid & 63;
    const float* W; int w, ks;
    if (slot < 32) {
        int m = slot >> 3;
        W = (m == 0) ? gp1 : (m == 1) ? gp2 : (m == 2) ? gv1 : gv2;
        w = (slot >> 1) & 3; ks = slot & 1;
    } else if (slot < 40) {
        W = pol1; w = (slot - 32) >> 1; ks = slot & 1;
    } else {
        int idx = slot - 40; W = val1; w = idx / 24; ks = idx % 24;
    }
    int dout = w * 16 + (l & 15);
    int k0 = ks * 32 + (l >> 4) * 8;
    bf16x8 v;
    #pragma unroll
    for (int i = 0; i < 8; ++i) v[i] = (__bf16)W[(size_t)(k0 + i) * 64 + dout];
    *(bf16x8*)(wsb + (size_t)gid * 8) = v;
}

// ---------------------------------------------------------------------------
// main kernel: 512 threads = 8 waves. Waves 0-3 = policy-branch tiles, 4-7 =
// value-branch tiles. Balanced schedule (R|R, W|W, heads split 7/7 units).
// Round-12 base + NEW: (512,3) bounds (VGPR cap 170; occupancy stays
// LDS-capped at 3 blocks/CU) + batched ds_reads in gcn_read (all 24 loads
// issued before the MFMA chain) + value-head loads hoisted. Same math/order.
// LDS = 2*24576 + 2816 + 256 = 52224 B -> 3 blocks/CU.
// ---------------------------------------------------------------------------
__global__ __launch_bounds__(512, 3) void nervenet_mfma(
    const float* __restrict__ obs, const float* __restrict__ adjn,
    const float* __restrict__ w_in_t, const float* __restrict__ b_in_t,
    const float* __restrict__ w_in_j, const float* __restrict__ b_in_j,
    const float* __restrict__ b_gp1, const float* __restrict__ b_gp2,
    const float* __restrict__ b_gv1, const float* __restrict__ b_gv2,
    const float* __restrict__ b_pol1, const float* __restrict__ w_pol2, const float* __restrict__ b_pol2,
    const float* __restrict__ b_val1, const float* __restrict__ w_val2, const float* __restrict__ b_val2,
    const __bf16* __restrict__ wsb, float* __restrict__ out)
{
    // [node][el][feat] bf16, rows 128 B, XOR-swizzled by (el&7)<<4
    __shared__ unsigned char X [NN * EPB * DD * 2];   // 24576: x -> xv1 -> xv2 (in place)
    __shared__ unsigned char XP[NN * EPB * DD * 2];   // 24576: xp1 -> xp2 (in place)
    __shared__ float polp[4 * 11 * EPB];              // 2816 policy partials
    __shared__ float valp[4 * EPB];                   // 256  value partials

    const int tid = threadIdx.x;
    const int l   = tid & 63;
    const int el  = l & 15;
    const int kg  = l >> 4;
    const int wv  = tid >> 6;        // 0..7
    const int w   = wv & 3;          // out-feature tile within branch
    const bool isP = wv < 4;
    const int b0  = blockIdx.x * EPB;
    const int swz = (el & 7) << 4;

    // adjacency coefficients: literal indices + uniform pointer -> scalar loads
    float ac[34];
    #pragma unroll
    for (int i = 0; i < 34; ++i) ac[i] = adjn[AC_N[i] * 12 + AC_M[i]];

    // ---- embed: all 8 waves, each thread 2 feats x 12 nodes, obs direct from global ----
    {
        const int ee = tid & 15, fg = tid >> 4;       // fg 0..31 -> feats fg*2, fg*2+1
        const int eswz = (ee & 7) << 4;
        const float* os = obs + (size_t)(b0 + ee) * OBSD;   // 112B rows, 16B-aligned
        f32x4 o0 = *(const f32x4*)(os);
        f32x4 o1 = *(const f32x4*)(os + 4);
        f32x4 o2 = *(const f32x4*)(os + 8);
        f32x4 o3 = *(const f32x4*)(os + 12);
        f32x4 o4 = *(const f32x4*)(os + 16);
        f32x4 o5 = *(const f32x4*)(os + 20);
        f32x4 o6 = *(const f32x4*)(os + 24);
        float tors[6] = {o0[0], o0[1], o0[2], o0[3], o1[0], o1[1]};
        float j0[11] = {o1[2], o2[0], o2[2], o3[0], o3[2], o4[0], o4[2], o5[0], o5[2], o6[0], o6[2]};
        float j1[11] = {o1[3], o2[1], o2[3], o3[1], o3[3], o4[1], o4[3], o5[1], o5[3], o6[1], o6[3]};

        float y0 = b_in_t[fg * 2], y1 = b_in_t[fg * 2 + 1];
        #pragma unroll
        for (int ff = 0; ff < 6; ++ff) {
            y0 = __builtin_fmaf(tors[ff], w_in_t[ff * DD + fg * 2], y0);
            y1 = __builtin_fmaf(tors[ff], w_in_t[ff * DD + fg * 2 + 1], y1);
        }
        bf16x2 t;
        t[0] = (__bf16)tanh_fast(y0); t[1] = (__bf16)tanh_fast(y1);
        *(bf16x2*)(&X[(0 * EPB + ee) * 128 + ((fg * 4) ^ eswz)]) = t;

        const float wj0a = w_in_j[fg * 2], wj0b = w_in_j[fg * 2 + 1];
        const float wj1a = w_in_j[DD + fg * 2], wj1b = w_in_j[DD + fg * 2 + 1];
        const float bja = b_in_j[fg * 2], bjb = b_in_j[fg * 2 + 1];
        #pragma unroll
        for (int n = 1; n < NN; ++n) {
            float ya = __builtin_fmaf(j1[n-1], wj1a, __builtin_fmaf(j0[n-1], wj0a, bja));
            float yb = __builtin_fmaf(j1[n-1], wj1b, __builtin_fmaf(j0[n-1], wj0b, bjb));
            t[0] = (__bf16)tanh_fast(ya); t[1] = (__bf16)tanh_fast(yb);
            *(bf16x2*)(&X[(n * EPB + ee) * 128 + ((fg * 4) ^ eswz)]) = t;
        }
    }

    auto rdfrag = [&](const unsigned char* buf, int n, int ks) {
        return *(const bf16x8*)(buf + (n * EPB + el) * 128 + ((ks * 64 + kg * 16) ^ swz));
    };
    auto ldws = [&](int slot) {
        return *(const bf16x8*)(wsb + ((size_t)slot * 64 + l) * 8);
    };

    // accumulators split into low/high f32x2 halves (element extracts only)
    f32x2 accL[NN], accH[NN];

    // batched read: issue ALL 24 ds_reads, then the MFMA chain (VGPR headroom
    // under (512,3) lets these stay live -> lgkmcnt waits amortize)
    auto gcn_read = [&](const unsigned char* src, int slotbase) {
        bf16x8 wf0 = ldws(slotbase + w * 2 + 0);
        bf16x8 wf1 = ldws(slotbase + w * 2 + 1);
        bf16x8 x0[NN], x1[NN];
        #pragma unroll
        for (int n = 0; n < NN; ++n) { x0[n] = rdfrag(src, n, 0); x1[n] = rdfrag(src, n, 1); }
        #pragma unroll
        for (int n = 0; n < NN; ++n) {
            f32x4 a = {0.f, 0.f, 0.f, 0.f};
            a = MFMA(wf0, x0[n], a);
            a = MFMA(wf1, x1[n], a);
            accL[n] = f32x2{a[0], a[1]};
            accH[n] = f32x2{a[2], a[3]};
        }
    };
    auto gcn_write = [&](unsigned char* dst, const float* bias) {
        f32x2 bv0 = *(const f32x2*)(bias + w * 16 + kg * 4);
        f32x2 bv1 = *(const f32x2*)(bias + w * 16 + kg * 4 + 2);
        #pragma unroll
        for (int n = 0; n < NN; ++n) {
            f32x2 y0 = bv0, y1 = bv1;
            #pragma unroll
            for (int j = AC_OFF[n]; j < AC_OFF[n + 1]; ++j) {
                const float a = ac[j];
                f32x2 a2 = {a, a};
                const int m = AC_M[j];
                y0 = __builtin_elementwise_fma(a2, accL[m], y0);   // v_pk_fma_f32
                y1 = __builtin_elementwise_fma(a2, accH[m], y1);
            }
            f32x2 t01 = tanh2_fast(y0);
            f32x2 t23 = tanh2_fast(y1);
            bf16x4 o;
            o[0] = (__bf16)t01[0]; o[1] = (__bf16)t01[1];
            o[2] = (__bf16)t23[0]; o[3] = (__bf16)t23[1];
            *(bf16x4*)(dst + (n * EPB + el) * 128 + (((w * 16 + kg * 4) * 2) ^ swz)) = o;
        }
    };

    unsigned char* MYBUF = isP ? XP : X;     // wave-uniform select

    __syncthreads();                         // B1: X = x ready
    gcn_read(X, isP ? 0 : 16);               // R1: both groups read X
    __syncthreads();                         // B2: X fully read
    gcn_write(MYBUF, isP ? b_gp1 : b_gv1);   // W1: p -> XP (fresh), v -> X (in place)
    __syncthreads();                         // B3: layer-1 outputs visible
    gcn_read(MYBUF, isP ? 8 : 24);           // R2: p reads XP, v reads X
    __syncthreads();                         // B4: buffers fully read
    gcn_write(MYBUF, isP ? b_gp2 : b_gv2);   // W2: in place
    __syncthreads();                         // B5: xp2 in XP, xv2 in X

    // ---- heads, balanced: all 8 waves run policy units (0-3: nj 0..6, 4-7: nj 7..10);
    //      waves 4-7 additionally run the value head. (~7 units each)
    {
        f32x4 bp  = *(const f32x4*)(b_pol1 + w * 16 + kg * 4);
        f32x4 wp2 = *(const f32x4*)(w_pol2 + w * 16 + kg * 4);
        bf16x8 pf0 = ldws(32 + w * 2 + 0);
        bf16x8 pf1 = ldws(32 + w * 2 + 1);
        auto pol_unit = [&](int nj) {
            bf16x8 x0 = rdfrag(XP, nj + 1, 0);
            bf16x8 x1 = rdfrag(XP, nj + 1, 1);
            f32x4 a = bp;
            a = MFMA(pf0, x0, a);
            a = MFMA(pf1, x1, a);
            float p = 0.f;
            #pragma unroll
            for (int r = 0; r < 4; ++r) p += tanh_fast(a[r]) * wp2[r];
            p += __shfl_xor(p, 16);
            p += __shfl_xor(p, 32);
            if (kg == 0) polp[w * 176 + nj * 16 + el] = p;
        };
        if (isP) {
            #pragma unroll
            for (int nj = 0; nj < 7; ++nj) pol_unit(nj);
        } else {
            #pragma unroll
            for (int nj = 7; nj < 11; ++nj) pol_unit(nj);
            // value head on X (= xv2): all weight-frag loads hoisted ahead of chain
            bf16x8 vwf[12];
            #pragma unroll
            for (int ks = 0; ks < 12; ++ks) vwf[ks] = ldws(40 + w * 24 + 2 * ks + (ks & 1));
            // note: slots used pairwise below exactly as before (40 + w*24 + ks)
            f32x4 a0 = *(const f32x4*)(b_val1 + w * 16 + kg * 4);
            f32x4 a1 = {0.f, 0.f, 0.f, 0.f};
            bf16x8 wfa[12];
            #pragma unroll
            for (int ks = 0; ks < 12; ++ks) wfa[ks] = ldws(40 + w * 24 + 2 * ks);
            #pragma unroll
            for (int ks = 0; ks < 12; ++ks) vwf[ks] = ldws(40 + w * 24 + 2 * ks + 1);
            #pragma unroll
            for (int n = 0; n < NN; ++n) {
                bf16x8 xf0 = rdfrag(X, n, 0);
                bf16x8 xf1 = rdfrag(X, n, 1);
                if ((n & 1) == 0) { a0 = MFMA(wfa[n], xf0, a0); a0 = MFMA(vwf[n], xf1, a0); }
                else              { a1 = MFMA(wfa[n], xf0, a1); a1 = MFMA(vwf[n], xf1, a1); }
            }
            f32x4 wv2 = *(const f32x4*)(w_val2 + w * 16 + kg * 4);
            float p = 0.f;
            #pragma unroll
            for (int r = 0; r < 4; ++r) p += tanh_fast(a0[r] + a1[r]) * wv2[r];
            p += __shfl_xor(p, 16);
            p += __shfl_xor(p, 32);
            if (kg == 0) valp[w * 16 + el] = p;
        }
    }
    __syncthreads();                         // B6: partials ready

    if (tid < 176) {
        int e2 = tid / 11, nj = tid - e2 * 11;
        out[(size_t)b0 * 11 + tid] =
            polp[nj * 16 + e2] + polp[176 + nj * 16 + e2] +
            polp[352 + nj * 16 + e2] + polp[528 + nj * 16 + e2] + b_pol2[0];
    }
    if (tid >= 192 && tid < 192 + EPB) {
        int e2 = tid - 192;
        out[(size_t)NB * 11 + b0 + e2] =
            valp[e2] + valp[16 + e2] + valp[32 + e2] + valp[48 + e2] + b_val2[0];
    }
}

extern "C" void kernel_launch(void* const* d_in, const int* in_sizes, int n_in,
                              void* d_out, int out_size, void* d_ws, size_t ws_size,
                              hipStream_t stream) {
    (void)in_sizes; (void)n_in; (void)out_size; (void)ws_size;
    const float** p = (const float**)d_in;
    __bf16* wsb = (__bf16*)d_ws;
    hipLaunchKernelGGL(prep_weights, dim3(34), dim3(256), 0, stream,
        p[6], p[8], p[10], p[12], p[14], p[18], wsb);
    hipLaunchKernelGGL(nervenet_mfma, dim3(NB / EPB), dim3(512), 0, stream,
        p[0], p[1], p[2], p[3], p[4], p[5],
        p[7], p[9], p[11], p[13],
        p[15], p[16], p[17],
        p[19], p[20], p[21],
        wsb, (float*)d_out);
}

// Round 14
// 55.899 us; speedup vs baseline: 1.0674x; 1.0674x over previous
//
#include <hip/hip_runtime.h>

#define NB 32768
#define NN 12
#define DD 64
#define OBSD 28
#define EPB 16            // batch elements per block (one MFMA N-tile)
#define NSLOT 136         // weight-fragment slots in d_ws

typedef __bf16 bf16x8 __attribute__((ext_vector_type(8)));
typedef __bf16 bf16x4 __attribute__((ext_vector_type(4)));
typedef __bf16 bf16x2 __attribute__((ext_vector_type(2)));
typedef float  f32x4  __attribute__((ext_vector_type(4)));
typedef float  f32x2  __attribute__((ext_vector_type(2)));

#define MFMA(a, b, c) __builtin_amdgcn_mfma_f32_16x16x32_bf16((a), (b), (c), 0, 0, 0)

__device__ __forceinline__ float tanh_fast(float x) {
    // tanh(x) = 1 - 2/(e^{2x}+1);  e^{2x} = 2^(x*2/ln2).  3 full-rate + 2 trans ops.
    float e = __builtin_amdgcn_exp2f(x * 2.885390081777927f);
    float r = __builtin_amdgcn_rcpf(e + 1.f);
    return __builtin_fmaf(-2.f, r, 1.f);
}

// pairwise tanh: packed full-rate ops (pk_mul/pk_add/pk_fma) around scalar trans
__device__ __forceinline__ f32x2 tanh2_fast(f32x2 x) {
    const f32x2 k   = {2.885390081777927f, 2.885390081777927f};
    const f32x2 one = {1.f, 1.f};
    const f32x2 m2  = {-2.f, -2.f};
    f32x2 xe = x * k;
    f32x2 e;
    e[0] = __builtin_amdgcn_exp2f(xe[0]);
    e[1] = __builtin_amdgcn_exp2f(xe[1]);
    f32x2 ep = e + one;
    f32x2 r;
    r[0] = __builtin_amdgcn_rcpf(ep[0]);
    r[1] = __builtin_amdgcn_rcpf(ep[1]);
    return __builtin_elementwise_fma(m2, r, one);
}

// adjacency sparsity (12 nodes, 11 edges + self loops = 34 nonzeros), grouped by output node
static constexpr int AC_OFF[13] = {0,5,8,11,13,16,19,21,24,27,29,32,34};
static constexpr int AC_M[34] = {0,1,4,7,10, 0,1,2, 1,2,3, 2,3, 0,4,5, 4,5,6, 5,6, 0,7,8, 7,8,9, 8,9, 0,10,11, 10,11};
static constexpr int AC_N[34] = {0,0,0,0,0, 1,1,1, 2,2,2, 3,3, 4,4,4, 5,5,5, 6,6, 7,7,7, 8,8,8, 9,9, 10,10,10, 11,11};

// ---------------------------------------------------------------------------
// prep: pack W^T into MFMA A-fragment layout, bf16, into d_ws.
// slot map: 0..31 gcn {gp1,gp2,gv1,gv2}: mat*8 + w*2 + ks
//           32..39 pol1: 32 + w*2 + ks
//           40..135 val1: 40 + w*24 + ks   (K=768 -> 24 ksteps)
// per (slot, lane): 8 bf16 = A[w*16 + (l&15)][ks*32 + (l>>4)*8 + i] = W[k][dout]
// ---------------------------------------------------------------------------
__global__ __launch_bounds__(256) void prep_weights(
    const float* __restrict__ gp1, const float* __restrict__ gp2,
    const float* __restrict__ gv1, const float* __restrict__ gv2,
    const float* __restrict__ pol1, const float* __restrict__ val1,
    __bf16* __restrict__ wsb)
{
    int gid = blockIdx.x * blockDim.x + threadIdx.x;
    if (gid >= NSLOT * 64) return;
    int slot = gid >> 6, l = gid & 63;
    const float* W; int w, ks;
    if (slot < 32) {
        int m = slot >> 3;
        W = (m == 0) ? gp1 : (m == 1) ? gp2 : (m == 2) ? gv1 : gv2;
        w = (slot >> 1) & 3; ks = slot & 1;
    } else if (slot < 40) {
        W = pol1; w = (slot - 32) >> 1; ks = slot & 1;
    } else {
        int idx = slot - 40; W = val1; w = idx / 24; ks = idx % 24;
    }
    int dout = w * 16 + (l & 15);
    int k0 = ks * 32 + (l >> 4) * 8;
    bf16x8 v;
    #pragma unroll
    for (int i = 0; i < 8; ++i) v[i] = (__bf16)W[(size_t)(k0 + i) * 64 + dout];
    *(bf16x8*)(wsb + (size_t)gid * 8) = v;
}

// ---------------------------------------------------------------------------
// main kernel: 512 threads = 8 waves. Waves 0-3 = policy-branch tiles, 4-7 =
// value-branch tiles. Balanced schedule (R|R, W|W, heads split 7/7 units).
// Best-measured configuration (round 12, 55.96us): (512,4) bounds, tanh2
// packed pairs, pk-fma mix on split accumulators, node-major swizzled LDS,
// interleaved read/MFMA (compiler schedules lgkmcnt fine-grained).
// LDS = 2*24576 + 2816 + 256 = 52224 B -> 3 blocks/CU.
// ---------------------------------------------------------------------------
__global__ __launch_bounds__(512, 4) void nervenet_mfma(
    const float* __restrict__ obs, const float* __restrict__ adjn,
    const float* __restrict__ w_in_t, const float* __restrict__ b_in_t,
    const float* __restrict__ w_in_j, const float* __restrict__ b_in_j,
    const float* __restrict__ b_gp1, const float* __restrict__ b_gp2,
    const float* __restrict__ b_gv1, const float* __restrict__ b_gv2,
    const float* __restrict__ b_pol1, const float* __restrict__ w_pol2, const float* __restrict__ b_pol2,
    const float* __restrict__ b_val1, const float* __restrict__ w_val2, const float* __restrict__ b_val2,
    const __bf16* __restrict__ wsb, float* __restrict__ out)
{
    // [node][el][feat] bf16, rows 128 B, XOR-swizzled by (el&7)<<4
    __shared__ unsigned char X [NN * EPB * DD * 2];   // 24576: x -> xv1 -> xv2 (in place)
    __shared__ unsigned char XP[NN * EPB * DD * 2];   // 24576: xp1 -> xp2 (in place)
    __shared__ float polp[4 * 11 * EPB];              // 2816 policy partials
    __shared__ float valp[4 * EPB];                   // 256  value partials

    const int tid = threadIdx.x;
    const int l   = tid & 63;
    const int el  = l & 15;
    const int kg  = l >> 4;
    const int wv  = tid >> 6;        // 0..7
    const int w   = wv & 3;          // out-feature tile within branch
    const bool isP = wv < 4;
    const int b0  = blockIdx.x * EPB;
    const int swz = (el & 7) << 4;

    // adjacency coefficients: literal indices + uniform pointer -> scalar loads
    float ac[34];
    #pragma unroll
    for (int i = 0; i < 34; ++i) ac[i] = adjn[AC_N[i] * 12 + AC_M[i]];

    // ---- embed: all 8 waves, each thread 2 feats x 12 nodes, obs direct from global ----
    {
        const int ee = tid & 15, fg = tid >> 4;       // fg 0..31 -> feats fg*2, fg*2+1
        const int eswz = (ee & 7) << 4;
        const float* os = obs + (size_t)(b0 + ee) * OBSD;   // 112B rows, 16B-aligned
        f32x4 o0 = *(const f32x4*)(os);
        f32x4 o1 = *(const f32x4*)(os + 4);
        f32x4 o2 = *(const f32x4*)(os + 8);
        f32x4 o3 = *(const f32x4*)(os + 12);
        f32x4 o4 = *(const f32x4*)(os + 16);
        f32x4 o5 = *(const f32x4*)(os + 20);
        f32x4 o6 = *(const f32x4*)(os + 24);
        float tors[6] = {o0[0], o0[1], o0[2], o0[3], o1[0], o1[1]};
        float j0[11] = {o1[2], o2[0], o2[2], o3[0], o3[2], o4[0], o4[2], o5[0], o5[2], o6[0], o6[2]};
        float j1[11] = {o1[3], o2[1], o2[3], o3[1], o3[3], o4[1], o4[3], o5[1], o5[3], o6[1], o6[3]};

        float y0 = b_in_t[fg * 2], y1 = b_in_t[fg * 2 + 1];
        #pragma unroll
        for (int ff = 0; ff < 6; ++ff) {
            y0 = __builtin_fmaf(tors[ff], w_in_t[ff * DD + fg * 2], y0);
            y1 = __builtin_fmaf(tors[ff], w_in_t[ff * DD + fg * 2 + 1], y1);
        }
        bf16x2 t;
        t[0] = (__bf16)tanh_fast(y0); t[1] = (__bf16)tanh_fast(y1);
        *(bf16x2*)(&X[(0 * EPB + ee) * 128 + ((fg * 4) ^ eswz)]) = t;

        const float wj0a = w_in_j[fg * 2], wj0b = w_in_j[fg * 2 + 1];
        const float wj1a = w_in_j[DD + fg * 2], wj1b = w_in_j[DD + fg * 2 + 1];
        const float bja = b_in_j[fg * 2], bjb = b_in_j[fg * 2 + 1];
        #pragma unroll
        for (int n = 1; n < NN; ++n) {
            float ya = __builtin_fmaf(j1[n-1], wj1a, __builtin_fmaf(j0[n-1], wj0a, bja));
            float yb = __builtin_fmaf(j1[n-1], wj1b, __builtin_fmaf(j0[n-1], wj0b, bjb));
            t[0] = (__bf16)tanh_fast(ya); t[1] = (__bf16)tanh_fast(yb);
            *(bf16x2*)(&X[(n * EPB + ee) * 128 + ((fg * 4) ^ eswz)]) = t;
        }
    }

    auto rdfrag = [&](const unsigned char* buf, int n, int ks) {
        return *(const bf16x8*)(buf + (n * EPB + el) * 128 + ((ks * 64 + kg * 16) ^ swz));
    };
    auto ldws = [&](int slot) {
        return *(const bf16x8*)(wsb + ((size_t)slot * 64 + l) * 8);
    };

    // accumulators split into low/high f32x2 halves (element extracts only)
    f32x2 accL[NN], accH[NN];

    auto gcn_read = [&](const unsigned char* src, int slotbase) {
        bf16x8 wf0 = ldws(slotbase + w * 2 + 0);
        bf16x8 wf1 = ldws(slotbase + w * 2 + 1);
        #pragma unroll
        for (int n = 0; n < NN; ++n) {
            bf16x8 x0 = rdfrag(src, n, 0);
            bf16x8 x1 = rdfrag(src, n, 1);
            f32x4 a = {0.f, 0.f, 0.f, 0.f};
            a = MFMA(wf0, x0, a);
            a = MFMA(wf1, x1, a);
            accL[n] = f32x2{a[0], a[1]};
            accH[n] = f32x2{a[2], a[3]};
        }
    };
    auto gcn_write = [&](unsigned char* dst, const float* bias) {
        f32x2 bv0 = *(const f32x2*)(bias + w * 16 + kg * 4);
        f32x2 bv1 = *(const f32x2*)(bias + w * 16 + kg * 4 + 2);
        #pragma unroll
        for (int n = 0; n < NN; ++n) {
            f32x2 y0 = bv0, y1 = bv1;
            #pragma unroll
            for (int j = AC_OFF[n]; j < AC_OFF[n + 1]; ++j) {
                const float a = ac[j];
                f32x2 a2 = {a, a};
                const int m = AC_M[j];
                y0 = __builtin_elementwise_fma(a2, accL[m], y0);   // v_pk_fma_f32
                y1 = __builtin_elementwise_fma(a2, accH[m], y1);
            }
            f32x2 t01 = tanh2_fast(y0);
            f32x2 t23 = tanh2_fast(y1);
            bf16x4 o;
            o[0] = (__bf16)t01[0]; o[1] = (__bf16)t01[1];
            o[2] = (__bf16)t23[0]; o[3] = (__bf16)t23[1];
            *(bf16x4*)(dst + (n * EPB + el) * 128 + (((w * 16 + kg * 4) * 2) ^ swz)) = o;
        }
    };

    unsigned char* MYBUF = isP ? XP : X;     // wave-uniform select

    __syncthreads();                         // B1: X = x ready
    gcn_read(X, isP ? 0 : 16);               // R1: both groups read X
    __syncthreads();                         // B2: X fully read
    gcn_write(MYBUF, isP ? b_gp1 : b_gv1);   // W1: p -> XP (fresh), v -> X (in place)
    __syncthreads();                         // B3: layer-1 outputs visible
    gcn_read(MYBUF, isP ? 8 : 24);           // R2: p reads XP, v reads X
    __syncthreads();                         // B4: buffers fully read
    gcn_write(MYBUF, isP ? b_gp2 : b_gv2);   // W2: in place
    __syncthreads();                         // B5: xp2 in XP, xv2 in X

    // ---- heads, balanced: all 8 waves run policy units (0-3: nj 0..6, 4-7: nj 7..10);
    //      waves 4-7 additionally run the value head. (~7 units each)
    {
        f32x4 bp  = *(const f32x4*)(b_pol1 + w * 16 + kg * 4);
        f32x4 wp2 = *(const f32x4*)(w_pol2 + w * 16 + kg * 4);
        bf16x8 pf0 = ldws(32 + w * 2 + 0);
        bf16x8 pf1 = ldws(32 + w * 2 + 1);
        auto pol_unit = [&](int nj) {
            bf16x8 x0 = rdfrag(XP, nj + 1, 0);
            bf16x8 x1 = rdfrag(XP, nj + 1, 1);
            f32x4 a = bp;
            a = MFMA(pf0, x0, a);
            a = MFMA(pf1, x1, a);
            float p = 0.f;
            #pragma unroll
            for (int r = 0; r < 4; ++r) p += tanh_fast(a[r]) * wp2[r];
            p += __shfl_xor(p, 16);
            p += __shfl_xor(p, 32);
            if (kg == 0) polp[w * 176 + nj * 16 + el] = p;
        };
        if (isP) {
            #pragma unroll
            for (int nj = 0; nj < 7; ++nj) pol_unit(nj);
        } else {
            #pragma unroll
            for (int nj = 7; nj < 11; ++nj) pol_unit(nj);
            // value head on X (= xv2)
            f32x4 a0 = *(const f32x4*)(b_val1 + w * 16 + kg * 4);
            f32x4 a1 = {0.f, 0.f, 0.f, 0.f};
            #pragma unroll 4
            for (int ks = 0; ks < 24; ks += 2) {
                bf16x8 wf0 = ldws(40 + w * 24 + ks);
                bf16x8 wf1 = ldws(40 + w * 24 + ks + 1);
                int n = ks >> 1;
                bf16x8 xf0 = rdfrag(X, n, 0);
                bf16x8 xf1 = rdfrag(X, n, 1);
                a0 = MFMA(wf0, xf0, a0);
                a1 = MFMA(wf1, xf1, a1);
            }
            f32x4 wv2 = *(const f32x4*)(w_val2 + w * 16 + kg * 4);
            float p = 0.f;
            #pragma unroll
            for (int r = 0; r < 4; ++r) p += tanh_fast(a0[r] + a1[r]) * wv2[r];
            p += __shfl_xor(p, 16);
            p += __shfl_xor(p, 32);
            if (kg == 0) valp[w * 16 + el] = p;
        }
    }
    __syncthreads();                         // B6: partials ready

    if (tid < 176) {
        int e2 = tid / 11, nj = tid - e2 * 11;
        out[(size_t)b0 * 11 + tid] =
            polp[nj * 16 + e2] + polp[176 + nj * 16 + e2] +
            polp[352 + nj * 16 + e2] + polp[528 + nj * 16 + e2] + b_pol2[0];
    }
    if (tid >= 192 && tid < 192 + EPB) {
        int e2 = tid - 192;
        out[(size_t)NB * 11 + b0 + e2] =
            valp[e2] + valp[16 + e2] + valp[32 + e2] + valp[48 + e2] + b_val2[0];
    }
}

extern "C" void kernel_launch(void* const* d_in, const int* in_sizes, int n_in,
                              void* d_out, int out_size, void* d_ws, size_t ws_size,
                              hipStream_t stream) {
    (void)in_sizes; (void)n_in; (void)out_size; (void)ws_size;
    const float** p = (const float**)d_in;
    __bf16* wsb = (__bf16*)d_ws;
    hipLaunchKernelGGL(prep_weights, dim3(34), dim3(256), 0, stream,
        p[6], p[8], p[10], p[12], p[14], p[18], wsb);
    hipLaunchKernelGGL(nervenet_mfma, dim3(NB / EPB), dim3(512), 0, stream,
        p[0], p[1], p[2], p[3], p[4], p[5],
        p[7], p[9], p[11], p[13],
        p[15], p[16], p[17],
        p[19], p[20], p[21],
        wsb, (float*)d_out);
}